// Round 7
// baseline (712.470 us; speedup 1.0000x reference)
//
#include <hip/hip_runtime.h>

// ---------------- types ----------------
typedef __bf16 bf16;
typedef __bf16 bf16x4 __attribute__((ext_vector_type(4)));
typedef __bf16 bf16x8 __attribute__((ext_vector_type(8)));
typedef float  f32x4  __attribute__((ext_vector_type(4)));

// Problem constants: b=64, a=8 -> 512 slices total, processed in 2 groups of SG=256.
// f=F=256 (DIM), t=T=256, 3*hidden=1536, heads=4, c=128
#define TT    256
#define FF    256
#define SG    256         // slices per group
#define NGRP  2

// scheduling primitives (k_out keeps the counted-vmcnt pipeline)
#define SCHED0 __builtin_amdgcn_sched_barrier(0)
#define BAR    __builtin_amdgcn_s_barrier()
#define WAITVM(N) asm volatile("s_waitcnt vmcnt(" #N ")" ::: "memory")

static __device__ inline f32x4 mfma16(bf16x8 a, bf16x8 b, f32x4 c) {
    return __builtin_amdgcn_mfma_f32_16x16x32_bf16(a, b, c, 0, 0, 0);
}

// ---- async global->LDS staging (16B per lane; LDS dest = wave-uniform base + lane*16) ----
typedef const __attribute__((address_space(1))) unsigned int* gp_t;
typedef __attribute__((address_space(3))) unsigned int* lp_t;
static __device__ inline void gll16(const bf16* g, bf16* l) {
    __builtin_amdgcn_global_load_lds((gp_t)g, (lp_t)l, 16, 0, 0);
}

// 4-wave stage of [128][32] bf16 tile (k_temb / k_out)
static __device__ inline void stage128g(const bf16* __restrict__ g, int ld, bf16* __restrict__ l) {
    int lane = threadIdx.x & 63, wv = threadIdx.x >> 6;
    int r = lane >> 2, c8 = (lane & 3) * 8;
#pragma unroll
    for (int i = 0; i < 2; i++) {
        int row0 = wv * 32 + i * 16;
        gll16(g + (size_t)(row0 + r) * ld + c8, l + row0 * 32);
    }
}
// 8-wave stage of [128][32] bf16 tile (fused kernel): wave w stages rows [w*16, w*16+16), 1 instr.
static __device__ inline void stage8(const bf16* __restrict__ g, int ld, bf16* __restrict__ l) {
    int lane = threadIdx.x & 63, wv = threadIdx.x >> 6;
    int r = lane >> 2, c8 = (lane & 3) * 8;
    int row0 = wv * 16;
    gll16(g + (size_t)(row0 + r) * ld + c8, l + row0 * 32);
}
// Fragment load from unpadded [rows][32] tile: lane holds row (row0 + lane&15), k = (lane>>4)*8 + j
static __device__ inline bf16x8 fragld(const bf16* __restrict__ l, int row0) {
    int lane = threadIdx.x & 63;
    return *(const bf16x8*)(l + (row0 + (lane & 15)) * 32 + (lane >> 4) * 8);
}
// Same but explicit stride (for the ct LDS round-trip)
static __device__ inline bf16x8 fragld_s(const bf16* __restrict__ l, int row0, int stride) {
    int lane = threadIdx.x & 63;
    return *(const bf16x8*)(l + (row0 + (lane & 15)) * stride + (lane >> 4) * 8);
}

// ---------------- small prep kernels ----------------
__global__ __launch_bounds__(256) void k_cvt(const float4* __restrict__ src, bf16* __restrict__ dst) {
    int i = blockIdx.x * 256 + threadIdx.x;
    float4 v = src[i];
    bf16x4 o;
    o[0] = (__bf16)v.x; o[1] = (__bf16)v.y; o[2] = (__bf16)v.z; o[3] = (__bf16)v.w;
    *(bf16x4*)(dst + (size_t)i * 4) = o;
}

__global__ __launch_bounds__(256) void k_mish(const float4* __restrict__ src, bf16* __restrict__ dst) {
    int i = blockIdx.x * 256 + threadIdx.x;
    float4 v = src[i];
    float in[4] = {v.x, v.y, v.z, v.w};
    bf16x4 o;
#pragma unroll
    for (int j = 0; j < 4; j++) {
        float sp = log1pf(__expf(in[j]));
        o[j] = (__bf16)(in[j] * tanhf(sp));
    }
    *(bf16x4*)(dst + (size_t)i * 4) = o;
}

// x [s][f][t] fp32 -> xT [s][t][f] bf16 (64x64 LDS tiles); grid = SG*16, s is group-local
__global__ __launch_bounds__(256) void k_xpose(const float* __restrict__ x, bf16* __restrict__ xT) {
    __shared__ float tile[64][65];
    int bid = blockIdx.x;
    int s  = bid >> 4;
    int f0 = ((bid >> 2) & 3) * 64;
    int t0 = (bid & 3) * 64;
    int tid = threadIdx.x;
    int rr = tid >> 4;
    int cc = (tid & 15) * 4;
    const float* xp = x + ((size_t)(s * FF + f0)) * TT + t0;
#pragma unroll
    for (int i = 0; i < 4; i++) {
        int r = i * 16 + rr;
        float4 v = *(const float4*)(xp + (size_t)r * TT + cc);
        tile[r][cc] = v.x; tile[r][cc + 1] = v.y; tile[r][cc + 2] = v.z; tile[r][cc + 3] = v.w;
    }
    __syncthreads();
    bf16* op = xT + ((size_t)(s * TT + t0)) * FF + f0;
#pragma unroll
    for (int i = 0; i < 4; i++) {
        int tr = i * 16 + rr;
        bf16x4 o;
        o[0] = (__bf16)tile[cc][tr];     o[1] = (__bf16)tile[cc + 1][tr];
        o[2] = (__bf16)tile[cc + 2][tr]; o[3] = (__bf16)tile[cc + 3][tr];
        *(bf16x4*)(op + (size_t)tr * FF + cc) = o;
    }
}

// ---------------- temb GEMM: tembT[o][sg] = w_time[o][:] . mish[sg][:] + b_time[o] ----------------
__global__ __launch_bounds__(256) void k_temb(const bf16* __restrict__ wt, const bf16* __restrict__ mish,
                                              const float* __restrict__ bt, float* __restrict__ tembT) {
    __shared__ bf16 lA[128 * 32];
    __shared__ bf16 lB[128 * 32];
    int o0 = blockIdx.x * 128, s0 = blockIdx.y * 128;
    int tid = threadIdx.x, wv = tid >> 6, lane = tid & 63, qd = lane >> 4, c = lane & 15;
    f32x4 acc[2][8] = {};
    for (int k0 = 0; k0 < 256; k0 += 32) {
        __syncthreads();
        stage128g(wt + (size_t)o0 * 256 + k0, 256, lA);
        stage128g(mish + (size_t)s0 * 256 + k0, 256, lB);
        __syncthreads();
        bf16x8 a0 = fragld(lA, wv * 32), a1 = fragld(lA, wv * 32 + 16);
#pragma unroll
        for (int nt = 0; nt < 8; nt++) {
            bf16x8 b = fragld(lB, nt * 16);
            acc[0][nt] = mfma16(a0, b, acc[0][nt]);
            acc[1][nt] = mfma16(a1, b, acc[1][nt]);
        }
    }
#pragma unroll
    for (int mt = 0; mt < 2; mt++)
#pragma unroll
        for (int nt = 0; nt < 8; nt++)
#pragma unroll
            for (int r = 0; r < 4; r++) {
                int o = o0 + wv * 32 + mt * 16 + qd * 4 + r;
                int s = s0 + nt * 16 + c;
                tembT[(size_t)o * 512 + s] = acc[mt][nt][r] + bt[o];
            }
}

// ---------------- fused qkv + attention per (s, h) ----------------
// grid SG*4 (XCD-chunk swizzled), 512 threads = 8 waves. Everything stays in LDS:
//   per t-half th: kv-GEMM (A=x rows t, B=W rows d; verified r4/r5 orientation)
//     -> lk/lv tiles [4][128 ch][32 t]; stats (online max/sum, combined across halves
//     with cacc rescale by exp(m_old-m_new)); phase-2 MFMA (A=v rows e, B=exp(k) rows d).
//   ct -> lct [128 e][136 d]; per th: q-GEMM (A=Wq rows d, B=x rows t) -> lq tiles
//     [4][128 t][32 d]; 3b MFMA (A=ct rows e, B=q rows t); midT epilogue.
// Eliminates the 402 MB q/k/v HBM round-trip + the k double-read.
__global__ __launch_bounds__(512) void k_fused(const bf16* __restrict__ wqkv, const bf16* __restrict__ xT,
                                               const float* __restrict__ tembT, bf16* __restrict__ midT) {
    __shared__ __align__(16) char smem[124928];
    bf16*  lx  = (bf16*)(smem);              // x-tile  [128 t][32 f]   8192 B
    bf16*  lwA = (bf16*)(smem + 8192);       // W-tile A                8192 B
    bf16*  lwB = (bf16*)(smem + 16384);      // W-tile B                8192 B
    float* mx  = (float*)(smem + 24576);     // [128] running max
    float* ls  = (float*)(smem + 25088);     // [128] running sum
    float* rs  = (float*)(smem + 25600);     // [128] 1/sum (final)
    float* rfb = (float*)(smem + 26112);     // [128] rescale factor
    bf16*  lk  = (bf16*)(smem + 26624);      // k tiles [4][128][32]   32768 B
    bf16*  lv  = (bf16*)(smem + 59392);      // v tiles [4][128][32]   32768 B
    bf16*  lq  = (bf16*)(smem + 92160);      // q tiles [4][128][32]   32768 B (ends 124928)
    bf16*  lct = (bf16*)(smem + 26624);      // ct [128][136] 34816 B, aliases lk(+lv head); both dead

    int b = blockIdx.x;
    int w = (b & 7) * (4 * SG / 8) + (b >> 3);   // XCD chunking, 4*SG % 8 == 0
    int s = w >> 2, h = w & 3;
    int tid = threadIdx.x, wv = tid >> 6, lane = tid & 63, qd = lane >> 4, c = lane & 15;
    const bf16* xs = xT + (size_t)s * (TT * FF);
    const bf16* Wq = wqkv + (size_t)(h * 128) * 256;
    const bf16* Wk = wqkv + (size_t)(512 + h * 128) * 256;
    const bf16* Wv = wqkv + (size_t)(1024 + h * 128) * 256;

    f32x4 cacc[8] = {};   // ct: row e = wv*16+qd*4+r, col d = nt*16+c

    for (int th = 0; th < 2; th++) {
        // ---- kv GEMM for t-half th ----
        f32x4 kacc[8] = {}, vacc[8] = {};
        const bf16* xh = xs + (size_t)th * 128 * 256;
        for (int f0 = 0; f0 < 256; f0 += 32) {
            __syncthreads();                    // staging bufs free
            stage8(xh + f0, 256, lx);
            stage8(Wk + f0, 256, lwA);
            stage8(Wv + f0, 256, lwB);
            __syncthreads();                    // tiles landed (vmcnt drained)
            bf16x8 a0 = fragld(lx, wv * 16);    // A = x, rows t
#pragma unroll
            for (int nt = 0; nt < 8; nt++) {
                kacc[nt] = mfma16(a0, fragld(lwA, nt * 16), kacc[nt]);
                vacc[nt] = mfma16(a0, fragld(lwB, nt * 16), vacc[nt]);
            }
        }
        // acc row t = wv*16+qd*4+r (in half), col ch = nt*16+c. Store to tiles [tc=wv>>1][ch][32 t].
        {
            float tbk[8], tbv[8];
#pragma unroll
            for (int nt = 0; nt < 8; nt++) {
                tbk[nt] = tembT[(size_t)(512 + h * 128 + nt * 16 + c) * 512 + s];
                tbv[nt] = tembT[(size_t)(1024 + h * 128 + nt * 16 + c) * 512 + s];
            }
            int addr0 = (wv >> 1) * 4096 + (wv & 1) * 16 + qd * 4;
#pragma unroll
            for (int nt = 0; nt < 8; nt++) {
                bf16x4 ok, ov;
#pragma unroll
                for (int r = 0; r < 4; r++) {
                    ok[r] = (__bf16)(kacc[nt][r] + tbk[nt]);
                    ov[r] = (__bf16)(vacc[nt][r] + tbv[nt]);
                }
                int ad = addr0 + (nt * 16 + c) * 32;
                *(bf16x4*)(lk + ad) = ok;
                *(bf16x4*)(lv + ad) = ov;
            }
        }
        __syncthreads();   // lk/lv visible
        // ---- stats for this half: d = tid>>2 owns a k-row; 4 lanes x 32 t each ----
        {
            int d = tid >> 2, q4 = tid & 3;
            const bf16* p = lk + q4 * 4096 + d * 32;
            float m = -3e38f, l = 0.f;
#pragma unroll
            for (int ci = 0; ci < 4; ci++) {
                bf16x8 v8 = *(const bf16x8*)(p + ci * 8);
                float xv[8]; float cm = -3e38f;
#pragma unroll
                for (int j2 = 0; j2 < 8; j2++) { xv[j2] = (float)v8[j2]; cm = fmaxf(cm, xv[j2]); }
                if (cm > m) { l *= __expf(m - cm); m = cm; }
#pragma unroll
                for (int j2 = 0; j2 < 8; j2++) l += __expf(xv[j2] - m);
            }
            float mo = __shfl_xor(m, 1), lo = __shfl_xor(l, 1);
            float M = fmaxf(m, mo); l = l * __expf(m - M) + lo * __expf(mo - M); m = M;
            mo = __shfl_xor(m, 2); lo = __shfl_xor(l, 2);
            M = fmaxf(m, mo); l = l * __expf(m - M) + lo * __expf(mo - M); m = M;
            if (q4 == 0) {
                if (th == 0) { mx[d] = m; ls[d] = l; }
                else {
                    float Mo = mx[d];
                    float M2 = fmaxf(Mo, m);
                    float rf = __expf(Mo - M2);
                    float L  = ls[d] * rf + l * __expf(m - M2);
                    mx[d] = M2; rs[d] = 1.0f / L; rfb[d] = rf;
                }
            }
        }
        __syncthreads();   // mx (and rfb at th=1) ready
        // ---- rescale previous-half contributions (th==1 only) ----
        if (th == 1) {
#pragma unroll
            for (int nt = 0; nt < 8; nt++) {
                float rf = rfb[nt * 16 + c];
#pragma unroll
                for (int r = 0; r < 4; r++) cacc[nt][r] *= rf;
            }
        }
        // ---- phase 2 partial: cacc += v · exp(k - mx) over this half's 4 tiles ----
#pragma unroll
        for (int tc = 0; tc < 4; tc++) {
            bf16x8 a0 = fragld(lv + tc * 4096, wv * 16);   // A = v, rows e
#pragma unroll
            for (int nt = 0; nt < 8; nt++) {
                bf16x8 kf = fragld(lk + tc * 4096, nt * 16);
                float md = mx[nt * 16 + c];
                bf16x8 bb;
#pragma unroll
                for (int j2 = 0; j2 < 8; j2++) bb[j2] = (__bf16)__expf((float)kf[j2] - md);
                cacc[nt] = mfma16(a0, bb, cacc[nt]);
            }
        }
        __syncthreads();   // done reading lk/lv before next half overwrites
    }

    // ---- ct -> lct [e][136 d], scaled by 1/sum (lk/lv dead) ----
#pragma unroll
    for (int nt = 0; nt < 8; nt++) {
        int d = nt * 16 + c;
        float rv = rs[d];
#pragma unroll
        for (int r = 0; r < 4; r++)
            lct[(wv * 16 + qd * 4 + r) * 136 + d] = (__bf16)(cacc[nt][r] * rv);
    }
    __syncthreads();

    // ---- q GEMM + out per t-half ----
    for (int th = 0; th < 2; th++) {
        f32x4 qacc[8] = {};
        const bf16* xh = xs + (size_t)th * 128 * 256;
        for (int f0 = 0; f0 < 256; f0 += 32) {
            __syncthreads();
            stage8(xh + f0, 256, lx);
            stage8(Wq + f0, 256, lwA);
            __syncthreads();
            bf16x8 a0 = fragld(lwA, wv * 16);   // A = Wq, rows d
#pragma unroll
            for (int nt = 0; nt < 8; nt++)
                qacc[nt] = mfma16(a0, fragld(lx, nt * 16), qacc[nt]);
        }
        // acc row d = wv*16+qd*4+r, col t = nt*16+c. Store tiles [dc=wv>>1][t][32 d].
        {
            float tbq[4];
#pragma unroll
            for (int r = 0; r < 4; r++)
                tbq[r] = tembT[(size_t)(h * 128 + wv * 16 + qd * 4 + r) * 512 + s];
            int addr0 = (wv >> 1) * 4096 + (wv & 1) * 16 + qd * 4;
#pragma unroll
            for (int nt = 0; nt < 8; nt++) {
                bf16x4 oq;
#pragma unroll
                for (int r = 0; r < 4; r++) oq[r] = (__bf16)(qacc[nt][r] + tbq[r]);
                *(bf16x4*)(lq + addr0 + (nt * 16 + c) * 32) = oq;
            }
        }
        __syncthreads();   // lq visible
        // ---- 3b: out[e][t-half] = sum_d ct[e][d] q[d][t] ----
        f32x4 oacc[8] = {};
#pragma unroll
        for (int dc = 0; dc < 4; dc++) {
            bf16x8 a0 = fragld_s(lct + dc * 32, wv * 16, 136);   // A = ct, rows e
#pragma unroll
            for (int nt = 0; nt < 8; nt++)
                oacc[nt] = mfma16(a0, fragld(lq + dc * 4096, nt * 16), oacc[nt]);
        }
        // epilogue: midT[s][t][h*128 + e], bf16x4 along e
#pragma unroll
        for (int nt = 0; nt < 8; nt++) {
            int t = th * 128 + nt * 16 + c;
            int e = wv * 16 + qd * 4;
            bf16x4 o;
#pragma unroll
            for (int r = 0; r < 4; r++) o[r] = (__bf16)oacc[nt][r];
            *(bf16x4*)(midT + ((size_t)s * 256 + t) * 512 + h * 128 + e) = o;
        }
        __syncthreads();   // 3b reads of lq done before next half overwrites
    }
}

// ---------------- final conv: y[s][o][t] = w_out[o][:] . mid[:][t] + b_out[o] ----------------
// Flat grid 4*SG with XCD swizzle. Mtile=128, Ntile=128, K=512 (16 tiles),
// counted-vmcnt pipeline (r3 form; scalar fp32 stores = 64B full-line runs).
__global__ __launch_bounds__(256) void k_out(const bf16* __restrict__ wo, const bf16* __restrict__ midT,
                                             const float* __restrict__ bo, float* __restrict__ y) {
    __shared__ bf16 lA[2][128 * 32];
    __shared__ bf16 lB[2][128 * 32];
    int b = blockIdx.x;
    int w = (b & 7) * (4 * SG / 8) + (b >> 3);    // XCD chunking, 4*SG % 8 == 0
    int s = w >> 2, j = w & 3;
    int o0 = (j >> 1) * 128, t0 = (j & 1) * 128;
    int tid = threadIdx.x, wv = tid >> 6, lane = tid & 63, qd = lane >> 4, c = lane & 15;
    const bf16* wA = wo + (size_t)o0 * 512;
    const bf16* ms = midT + (size_t)s * 131072 + (size_t)t0 * 512;  // 256*512
    f32x4 acc[2][8] = {};
    stage128g(wA, 512, lA[0]);
    stage128g(ms, 512, lB[0]);
    SCHED0;
    stage128g(wA + 32, 512, lA[1]);
    stage128g(ms + 32, 512, lB[1]);
    SCHED0;
#pragma unroll
    for (int t = 0; t < 16; t++) {
        if (t == 15) { WAITVM(0); } else { WAITVM(4); }
        SCHED0; BAR; SCHED0;
        bf16x8 a0 = fragld(lA[t & 1], wv * 32), a1 = fragld(lA[t & 1], wv * 32 + 16);
#pragma unroll
        for (int nt = 0; nt < 8; nt++) {
            bf16x8 bfr = fragld(lB[t & 1], nt * 16);
            acc[0][nt] = mfma16(a0, bfr, acc[0][nt]);
            acc[1][nt] = mfma16(a1, bfr, acc[1][nt]);
        }
        SCHED0; BAR; SCHED0;
        if (t + 2 < 16) {
            stage128g(wA + (t + 2) * 32, 512, lA[t & 1]);
            stage128g(ms + (t + 2) * 32, 512, lB[t & 1]);
        }
        SCHED0;
    }
    float bb[2][4];
#pragma unroll
    for (int mt = 0; mt < 2; mt++)
#pragma unroll
        for (int r = 0; r < 4; r++)
            bb[mt][r] = bo[o0 + wv * 32 + mt * 16 + qd * 4 + r];
#pragma unroll
    for (int mt = 0; mt < 2; mt++)
#pragma unroll
        for (int nt = 0; nt < 8; nt++)
#pragma unroll
            for (int r = 0; r < 4; r++) {
                int o = o0 + wv * 32 + mt * 16 + qd * 4 + r;
                int t = t0 + nt * 16 + c;
                y[((size_t)(s * 256 + o)) * 256 + t] = acc[mt][nt][r] + bb[mt][r];
            }
}

// ---------------- launch ----------------
extern "C" void kernel_launch(void* const* d_in, const int* in_sizes, int n_in,
                              void* d_out, int out_size, void* d_ws, size_t ws_size,
                              hipStream_t stream) {
    const float* x      = (const float*)d_in[0];
    const float* time_  = (const float*)d_in[1];
    const float* w_qkv  = (const float*)d_in[2];
    const float* w_time = (const float*)d_in[3];
    const float* b_time = (const float*)d_in[4];
    const float* w_out  = (const float*)d_in[5];
    const float* b_out  = (const float*)d_in[6];
    float* y = (float*)d_out;
    char* ws = (char*)d_ws;

    // Workspace layout (ws_size = 512 MiB). qkv intermediates eliminated by fusion.
    bf16*  wqkv_bf  = (bf16*)(ws + 0);            //   786432 B
    bf16*  wtime_bf = (bf16*)(ws + 786432);       //   786432 B
    bf16*  wout_bf  = (bf16*)(ws + 1572864);      //   262144 B
    bf16*  mish_bf  = (bf16*)(ws + 1835008);      //   262144 B
    float* tembT    = (float*)(ws + 2097152);     //  3145728 B  [1536][512] global
    bf16*  xT       = (bf16*)(ws + 5242880);      // 33554432 B  per group (read by k_fused)
    bf16*  midT     = (bf16*)(ws + 206569472);    // 67108864 B  per group (disjoint from xT)

    // global prep (once)
    k_cvt<<<384, 256, 0, stream>>>((const float4*)w_qkv, wqkv_bf);    // 393216 elts
    k_cvt<<<384, 256, 0, stream>>>((const float4*)w_time, wtime_bf);  // 393216
    k_cvt<<<128, 256, 0, stream>>>((const float4*)w_out, wout_bf);    // 131072
    k_mish<<<128, 256, 0, stream>>>((const float4*)time_, mish_bf);   // 131072
    k_temb<<<dim3(12, 4), 256, 0, stream>>>(wtime_bf, mish_bf, b_time, tembT);

    // per-group pipeline
    for (int g = 0; g < NGRP; g++) {
        const float* xg = x + (size_t)g * SG * FF * TT;
        float*       yg = y + (size_t)g * SG * 256 * TT;
        const float* tg = tembT + (size_t)g * SG;             // column offset into [1536][512]
        k_xpose<<<SG * 16, 256, 0, stream>>>(xg, xT);
        k_fused<<<SG * 4, 512, 0, stream>>>(wqkv_bf, xT, tg, midT);
        k_out<<<4 * SG, 256, 0, stream>>>(wout_bf, midT, b_out, yg);
    }
}

// Round 8
// 612.999 us; speedup vs baseline: 1.1623x; 1.1623x over previous
//
#include <hip/hip_runtime.h>

// ---------------- types ----------------
typedef __bf16 bf16;
typedef __bf16 bf16x4 __attribute__((ext_vector_type(4)));
typedef __bf16 bf16x8 __attribute__((ext_vector_type(8)));
typedef float  f32x4  __attribute__((ext_vector_type(4)));

// Problem constants: b=64, a=8 -> 512 slices total, processed in 2 groups of SG=256.
#define TT    256
#define FF    256
#define SG    256
#define NGRP  2

// padded derived-tile geometry (k/v/q tiles in k_fused): stride 40 elts = 80 B rows
// -> bank stride 20 (~2-way) instead of 32-elt/64 B rows -> bank stride 16 (8-way).
#define TSTR  40
#define TSZ   (128 * TSTR)   // elts per [128][40] tile

// scheduling primitives for the counted-vmcnt pipeline (T3+T4)
#define SCHED0 __builtin_amdgcn_sched_barrier(0)
#define BAR    __builtin_amdgcn_s_barrier()
#define WAITVM(N) asm volatile("s_waitcnt vmcnt(" #N ")" ::: "memory")
#define WAITLGKM0 asm volatile("s_waitcnt lgkmcnt(0)" ::: "memory")

static __device__ inline f32x4 mfma16(bf16x8 a, bf16x8 b, f32x4 c) {
    return __builtin_amdgcn_mfma_f32_16x16x32_bf16(a, b, c, 0, 0, 0);
}

// ---- async global->LDS staging (16B per lane; LDS dest = wave-uniform base + lane*16) ----
typedef const __attribute__((address_space(1))) unsigned int* gp_t;
typedef __attribute__((address_space(3))) unsigned int* lp_t;
static __device__ inline void gll16(const bf16* g, bf16* l) {
    __builtin_amdgcn_global_load_lds((gp_t)g, (lp_t)l, 16, 0, 0);
}

// 4-wave stage of [128][32] bf16 tile (k_temb / k_out): 2 vm-ops per wave.
static __device__ inline void stage128g(const bf16* __restrict__ g, int ld, bf16* __restrict__ l) {
    int lane = threadIdx.x & 63, wv = threadIdx.x >> 6;
    int r = lane >> 2, c8 = (lane & 3) * 8;
#pragma unroll
    for (int i = 0; i < 2; i++) {
        int row0 = wv * 32 + i * 16;
        gll16(g + (size_t)(row0 + r) * ld + c8, l + row0 * 32);
    }
}
// 8-wave stage of [128][32] bf16 tile (k_fused): wave w stages rows [w*16,w*16+16), 1 vm-op/wave.
static __device__ inline void stage8(const bf16* __restrict__ g, int ld, bf16* __restrict__ l) {
    int lane = threadIdx.x & 63, wv = threadIdx.x >> 6;
    int r = lane >> 2, c8 = (lane & 3) * 8;
    int row0 = wv * 16;
    gll16(g + (size_t)(row0 + r) * ld + c8, l + row0 * 32);
}
// Fragment load from unpadded [rows][32] tile
static __device__ inline bf16x8 fragld(const bf16* __restrict__ l, int row0) {
    int lane = threadIdx.x & 63;
    return *(const bf16x8*)(l + (row0 + (lane & 15)) * 32 + (lane >> 4) * 8);
}
// Fragment load with explicit stride (padded tiles / lct)
static __device__ inline bf16x8 fragld_s(const bf16* __restrict__ l, int row0, int stride) {
    int lane = threadIdx.x & 63;
    return *(const bf16x8*)(l + (row0 + (lane & 15)) * stride + (lane >> 4) * 8);
}

// ---------------- small prep kernels ----------------
__global__ __launch_bounds__(256) void k_cvt(const float4* __restrict__ src, bf16* __restrict__ dst) {
    int i = blockIdx.x * 256 + threadIdx.x;
    float4 v = src[i];
    bf16x4 o;
    o[0] = (__bf16)v.x; o[1] = (__bf16)v.y; o[2] = (__bf16)v.z; o[3] = (__bf16)v.w;
    *(bf16x4*)(dst + (size_t)i * 4) = o;
}

__global__ __launch_bounds__(256) void k_mish(const float4* __restrict__ src, bf16* __restrict__ dst) {
    int i = blockIdx.x * 256 + threadIdx.x;
    float4 v = src[i];
    float in[4] = {v.x, v.y, v.z, v.w};
    bf16x4 o;
#pragma unroll
    for (int j = 0; j < 4; j++) {
        float sp = log1pf(__expf(in[j]));
        o[j] = (__bf16)(in[j] * tanhf(sp));
    }
    *(bf16x4*)(dst + (size_t)i * 4) = o;
}

// x [s][f][t] fp32 -> xT [s][t][f] bf16
__global__ __launch_bounds__(256) void k_xpose(const float* __restrict__ x, bf16* __restrict__ xT) {
    __shared__ float tile[64][65];
    int bid = blockIdx.x;
    int s  = bid >> 4;
    int f0 = ((bid >> 2) & 3) * 64;
    int t0 = (bid & 3) * 64;
    int tid = threadIdx.x;
    int rr = tid >> 4;
    int cc = (tid & 15) * 4;
    const float* xp = x + ((size_t)(s * FF + f0)) * TT + t0;
#pragma unroll
    for (int i = 0; i < 4; i++) {
        int r = i * 16 + rr;
        float4 v = *(const float4*)(xp + (size_t)r * TT + cc);
        tile[r][cc] = v.x; tile[r][cc + 1] = v.y; tile[r][cc + 2] = v.z; tile[r][cc + 3] = v.w;
    }
    __syncthreads();
    bf16* op = xT + ((size_t)(s * TT + t0)) * FF + f0;
#pragma unroll
    for (int i = 0; i < 4; i++) {
        int tr = i * 16 + rr;
        bf16x4 o;
        o[0] = (__bf16)tile[cc][tr];     o[1] = (__bf16)tile[cc + 1][tr];
        o[2] = (__bf16)tile[cc + 2][tr]; o[3] = (__bf16)tile[cc + 3][tr];
        *(bf16x4*)(op + (size_t)tr * FF + cc) = o;
    }
}

// ---------------- temb GEMM ----------------
__global__ __launch_bounds__(256) void k_temb(const bf16* __restrict__ wt, const bf16* __restrict__ mish,
                                              const float* __restrict__ bt, float* __restrict__ tembT) {
    __shared__ bf16 lA[128 * 32];
    __shared__ bf16 lB[128 * 32];
    int o0 = blockIdx.x * 128, s0 = blockIdx.y * 128;
    int tid = threadIdx.x, wv = tid >> 6, lane = tid & 63, qd = lane >> 4, c = lane & 15;
    f32x4 acc[2][8] = {};
    for (int k0 = 0; k0 < 256; k0 += 32) {
        __syncthreads();
        stage128g(wt + (size_t)o0 * 256 + k0, 256, lA);
        stage128g(mish + (size_t)s0 * 256 + k0, 256, lB);
        __syncthreads();
        bf16x8 a0 = fragld(lA, wv * 32), a1 = fragld(lA, wv * 32 + 16);
#pragma unroll
        for (int nt = 0; nt < 8; nt++) {
            bf16x8 b = fragld(lB, nt * 16);
            acc[0][nt] = mfma16(a0, b, acc[0][nt]);
            acc[1][nt] = mfma16(a1, b, acc[1][nt]);
        }
    }
#pragma unroll
    for (int mt = 0; mt < 2; mt++)
#pragma unroll
        for (int nt = 0; nt < 8; nt++)
#pragma unroll
            for (int r = 0; r < 4; r++) {
                int o = o0 + wv * 32 + mt * 16 + qd * 4 + r;
                int s = s0 + nt * 16 + c;
                tembT[(size_t)o * 512 + s] = acc[mt][nt][r] + bt[o];
            }
}

// ---------------- fused qkv + attention per (s, h) ----------------
// 512 threads = 8 waves, grid SG*4 XCD-swizzled. v2 fixes vs r6:
//  (1) exp-pass: exp(k-mx) computed ONCE into the LDS k-tile (was recomputed by every
//      wave inside phase-2: 16x redundant exp+cvt VALU work).
//  (2) derived k/v/q tiles padded to stride 40 (80B rows) -> ~2-way bank access on
//      both bf16x4 stores and b128 fragment reads (was 8-way; 3.0e7 conflict cycles).
//  (3) kv/q staging loops use the counted-vmcnt pipeline (no mid-loop vmcnt(0) drains).
// LDS map (133120 B total):
//   0      : staging 6 x [128][32] = 49152   (lx/lwA/lwB double-buffered)
//   49152  : mx[128] | 49664 ls | 50176 rs | 50688 rfb   (2048)
//   51200  : lk 4 x [128][40] = 40960        (lct [128][136]=34816 aliases, lk dead)
//   92160  : lv 4 x [128][40] = 40960        (lq aliases, lv dead)
#define LXF(i)  ((bf16*)(smem + (size_t)(i) * 8192))
#define LWAF(i) ((bf16*)(smem + 16384 + (size_t)(i) * 8192))
#define LWBF(i) ((bf16*)(smem + 32768 + (size_t)(i) * 8192))
__global__ __launch_bounds__(512) void k_fused(const bf16* __restrict__ wqkv, const bf16* __restrict__ xT,
                                               const float* __restrict__ tembT, bf16* __restrict__ midT) {
    __shared__ __align__(16) char smem[133120];
    float* mx  = (float*)(smem + 49152);
    float* ls  = (float*)(smem + 49664);
    float* rs  = (float*)(smem + 50176);
    float* rfb = (float*)(smem + 50688);
    bf16*  lk  = (bf16*)(smem + 51200);
    bf16*  lct = (bf16*)(smem + 51200);
    bf16*  lv  = (bf16*)(smem + 92160);
    bf16*  lq  = (bf16*)(smem + 92160);

    int b = blockIdx.x;
    int w = (b & 7) * (4 * SG / 8) + (b >> 3);   // XCD chunking
    int s = w >> 2, h = w & 3;
    int tid = threadIdx.x, wv = tid >> 6, lane = tid & 63, qd = lane >> 4, c = lane & 15;
    const bf16* xs = xT + (size_t)s * (TT * FF);
    const bf16* Wq = wqkv + (size_t)(h * 128) * 256;
    const bf16* Wk = wqkv + (size_t)(512 + h * 128) * 256;
    const bf16* Wv = wqkv + (size_t)(1024 + h * 128) * 256;

    f32x4 cacc[8] = {};   // ct: row e = wv*16+qd*4+r, col d = nt*16+c

    for (int th = 0; th < 2; th++) {
        // ---- kv GEMM for t-half th (counted-vmcnt; 3 vm-ops/wave/tile) ----
        f32x4 kacc[8] = {}, vacc[8] = {};
        const bf16* xh = xs + (size_t)th * 128 * 256;
        stage8(xh, 256, LXF(0)); stage8(Wk, 256, LWAF(0)); stage8(Wv, 256, LWBF(0));
        SCHED0;
        stage8(xh + 32, 256, LXF(1)); stage8(Wk + 32, 256, LWAF(1)); stage8(Wv + 32, 256, LWBF(1));
        SCHED0;
#pragma unroll
        for (int t = 0; t < 8; t++) {
            if (t == 7) { WAITVM(0); } else { WAITVM(3); }
            SCHED0; BAR; SCHED0;
            bf16x8 a0 = fragld(LXF(t & 1), wv * 16);       // A = x, rows t
#pragma unroll
            for (int nt = 0; nt < 8; nt++) {
                kacc[nt] = mfma16(a0, fragld(LWAF(t & 1), nt * 16), kacc[nt]);
                vacc[nt] = mfma16(a0, fragld(LWBF(t & 1), nt * 16), vacc[nt]);
            }
            SCHED0; BAR; SCHED0;
            if (t + 2 < 8) {
                stage8(xh + (t + 2) * 32, 256, LXF(t & 1));
                stage8(Wk + (t + 2) * 32, 256, LWAF(t & 1));
                stage8(Wv + (t + 2) * 32, 256, LWBF(t & 1));
            }
            SCHED0;
        }
        // store k/v (+bias) to padded tiles: tile tc=wv>>1 holds t in [32tc,32tc+32)
        {
            float tbk[8], tbv[8];
#pragma unroll
            for (int nt = 0; nt < 8; nt++) {
                tbk[nt] = tembT[(size_t)(512 + h * 128 + nt * 16 + c) * 512 + s];
                tbv[nt] = tembT[(size_t)(1024 + h * 128 + nt * 16 + c) * 512 + s];
            }
            int addr0 = (wv >> 1) * TSZ + (wv & 1) * 16 + qd * 4;
#pragma unroll
            for (int nt = 0; nt < 8; nt++) {
                bf16x4 ok, ov;
#pragma unroll
                for (int r = 0; r < 4; r++) {
                    ok[r] = (__bf16)(kacc[nt][r] + tbk[nt]);
                    ov[r] = (__bf16)(vacc[nt][r] + tbv[nt]);
                }
                int ad = addr0 + (nt * 16 + c) * TSTR;
                *(bf16x4*)(lk + ad) = ok;
                *(bf16x4*)(lv + ad) = ov;
            }
        }
        __syncthreads();   // lk/lv visible
        // ---- stats: d = tid>>2 owns a k-row; lane q4=tid&3 scans tile q4 (32 t's) ----
        {
            int d = tid >> 2, q4 = tid & 3;
            const bf16* p = lk + q4 * TSZ + d * TSTR;
            float m = -3e38f, l = 0.f;
#pragma unroll
            for (int ci = 0; ci < 4; ci++) {
                bf16x8 v8 = *(const bf16x8*)(p + ci * 8);
                float xv[8]; float cm = -3e38f;
#pragma unroll
                for (int j2 = 0; j2 < 8; j2++) { xv[j2] = (float)v8[j2]; cm = fmaxf(cm, xv[j2]); }
                if (cm > m) { l *= __expf(m - cm); m = cm; }
#pragma unroll
                for (int j2 = 0; j2 < 8; j2++) l += __expf(xv[j2] - m);
            }
            float mo = __shfl_xor(m, 1), lo = __shfl_xor(l, 1);
            float M = fmaxf(m, mo); l = l * __expf(m - M) + lo * __expf(mo - M); m = M;
            mo = __shfl_xor(m, 2); lo = __shfl_xor(l, 2);
            M = fmaxf(m, mo); l = l * __expf(m - M) + lo * __expf(mo - M); m = M;
            if (q4 == 0) {
                if (th == 0) { mx[d] = m; ls[d] = l; }
                else {
                    float Mo = mx[d];
                    float M2 = fmaxf(Mo, m);
                    float rf = __expf(Mo - M2);
                    float L  = ls[d] * rf + l * __expf(m - M2);
                    mx[d] = M2; rs[d] = 1.0f / L; rfb[d] = rf;
                }
            }
        }
        __syncthreads();   // mx (and rfb at th=1) ready
        // ---- exp-pass: lk <- exp(lk - mx[row]) in place; one row per thread ----
        {
            int tc2 = tid >> 7, ch = tid & 127;
            bf16* pr = lk + tc2 * TSZ + ch * TSTR;
            float md = mx[ch];
#pragma unroll
            for (int j2 = 0; j2 < 4; j2++) {
                bf16x8 v8 = *(const bf16x8*)(pr + j2 * 8);
                bf16x8 o8;
#pragma unroll
                for (int e2 = 0; e2 < 8; e2++) o8[e2] = (__bf16)__expf((float)v8[e2] - md);
                *(bf16x8*)(pr + j2 * 8) = o8;
            }
        }
        // rescale previous-half contributions (th==1 only) while exp-pass stores drain
        if (th == 1) {
#pragma unroll
            for (int nt = 0; nt < 8; nt++) {
                float rf = rfb[nt * 16 + c];
#pragma unroll
                for (int r = 0; r < 4; r++) cacc[nt][r] *= rf;
            }
        }
        __syncthreads();   // expk visible
        // ---- phase 2: cacc += v · expk over this half's 4 t-tiles (pure ds_read+MFMA) ----
#pragma unroll
        for (int tc = 0; tc < 4; tc++) {
            bf16x8 a0 = fragld_s(lv + tc * TSZ, wv * 16, TSTR);   // A = v, rows e
#pragma unroll
            for (int nt = 0; nt < 8; nt++)
                cacc[nt] = mfma16(a0, fragld_s(lk + tc * TSZ, nt * 16, TSTR), cacc[nt]);
        }
        __syncthreads();   // done reading lk/lv before next half overwrites
    }

    // ---- ct -> lct [e][136 d], scaled by 1/sum (lk dead) ----
#pragma unroll
    for (int nt = 0; nt < 8; nt++) {
        int d = nt * 16 + c;
        float rv = rs[d];
#pragma unroll
        for (int r = 0; r < 4; r++)
            lct[(wv * 16 + qd * 4 + r) * 136 + d] = (__bf16)(cacc[nt][r] * rv);
    }
    __syncthreads();

    // ---- q GEMM + out per t-half (counted-vmcnt; 2 vm-ops/wave/tile) ----
    for (int th = 0; th < 2; th++) {
        f32x4 qacc[8] = {};
        const bf16* xh = xs + (size_t)th * 128 * 256;
        stage8(xh, 256, LXF(0)); stage8(Wq, 256, LWAF(0));
        SCHED0;
        stage8(xh + 32, 256, LXF(1)); stage8(Wq + 32, 256, LWAF(1));
        SCHED0;
#pragma unroll
        for (int t = 0; t < 8; t++) {
            if (t == 7) { WAITVM(0); } else { WAITVM(2); }   // th=1: older midT stores drain first (safe)
            SCHED0; BAR; SCHED0;
            bf16x8 a0 = fragld(LWAF(t & 1), wv * 16);   // A = Wq, rows d
#pragma unroll
            for (int nt = 0; nt < 8; nt++)
                qacc[nt] = mfma16(a0, fragld(LXF(t & 1), nt * 16), qacc[nt]);
            SCHED0; BAR; SCHED0;
            if (t + 2 < 8) {
                stage8(xh + (t + 2) * 32, 256, LXF(t & 1));
                stage8(Wq + (t + 2) * 32, 256, LWAF(t & 1));
            }
            SCHED0;
        }
        // store q (+bias) to padded tiles: tile dc=wv>>1 holds d in [32dc,32dc+32), rows t
        {
            float tbq[4];
#pragma unroll
            for (int r = 0; r < 4; r++)
                tbq[r] = tembT[(size_t)(h * 128 + wv * 16 + qd * 4 + r) * 512 + s];
            int addr0 = (wv >> 1) * TSZ + (wv & 1) * 16 + qd * 4;
#pragma unroll
            for (int nt = 0; nt < 8; nt++) {
                bf16x4 oq;
#pragma unroll
                for (int r = 0; r < 4; r++) oq[r] = (__bf16)(qacc[nt][r] + tbq[r]);
                *(bf16x4*)(lq + addr0 + (nt * 16 + c) * TSTR) = oq;
            }
        }
        __syncthreads();   // lq visible
        // ---- 3b: out[e][t-half] = sum_d ct[e][d] q[d][t] ----
        f32x4 oacc[8] = {};
#pragma unroll
        for (int dc = 0; dc < 4; dc++) {
            bf16x8 a0 = fragld_s(lct + dc * 32, wv * 16, 136);   // A = ct, rows e
#pragma unroll
            for (int nt = 0; nt < 8; nt++)
                oacc[nt] = mfma16(a0, fragld_s(lq + dc * TSZ, nt * 16, TSTR), oacc[nt]);
        }
        // epilogue: midT[s][t][h*128 + e], bf16x4 along e
#pragma unroll
        for (int nt = 0; nt < 8; nt++) {
            int t = th * 128 + nt * 16 + c;
            int e = wv * 16 + qd * 4;
            bf16x4 o;
#pragma unroll
            for (int r = 0; r < 4; r++) o[r] = (__bf16)oacc[nt][r];
            *(bf16x4*)(midT + ((size_t)s * 256 + t) * 512 + h * 128 + e) = o;
        }
        __syncthreads();   // 3b reads of lq done before next half overwrites
    }
}

// ---------------- final conv: y[s][o][t] = w_out[o][:] . mid[:][t] + b_out[o] ----------------
__global__ __launch_bounds__(256) void k_out(const bf16* __restrict__ wo, const bf16* __restrict__ midT,
                                             const float* __restrict__ bo, float* __restrict__ y) {
    __shared__ bf16 lA[2][128 * 32];
    __shared__ bf16 lB[2][128 * 32];
    int b = blockIdx.x;
    int w = (b & 7) * (4 * SG / 8) + (b >> 3);    // XCD chunking
    int s = w >> 2, j = w & 3;
    int o0 = (j >> 1) * 128, t0 = (j & 1) * 128;
    int tid = threadIdx.x, wv = tid >> 6, lane = tid & 63, qd = lane >> 4, c = lane & 15;
    const bf16* wA = wo + (size_t)o0 * 512;
    const bf16* ms = midT + (size_t)s * 131072 + (size_t)t0 * 512;
    f32x4 acc[2][8] = {};
    stage128g(wA, 512, lA[0]);
    stage128g(ms, 512, lB[0]);
    SCHED0;
    stage128g(wA + 32, 512, lA[1]);
    stage128g(ms + 32, 512, lB[1]);
    SCHED0;
#pragma unroll
    for (int t = 0; t < 16; t++) {
        if (t == 15) { WAITVM(0); } else { WAITVM(4); }
        SCHED0; BAR; SCHED0;
        bf16x8 a0 = fragld(lA[t & 1], wv * 32), a1 = fragld(lA[t & 1], wv * 32 + 16);
#pragma unroll
        for (int nt = 0; nt < 8; nt++) {
            bf16x8 bfr = fragld(lB[t & 1], nt * 16);
            acc[0][nt] = mfma16(a0, bfr, acc[0][nt]);
            acc[1][nt] = mfma16(a1, bfr, acc[1][nt]);
        }
        SCHED0; BAR; SCHED0;
        if (t + 2 < 16) {
            stage128g(wA + (t + 2) * 32, 512, lA[t & 1]);
            stage128g(ms + (t + 2) * 32, 512, lB[t & 1]);
        }
        SCHED0;
    }
    float bb[2][4];
#pragma unroll
    for (int mt = 0; mt < 2; mt++)
#pragma unroll
        for (int r = 0; r < 4; r++)
            bb[mt][r] = bo[o0 + wv * 32 + mt * 16 + qd * 4 + r];
#pragma unroll
    for (int mt = 0; mt < 2; mt++)
#pragma unroll
        for (int nt = 0; nt < 8; nt++)
#pragma unroll
            for (int r = 0; r < 4; r++) {
                int o = o0 + wv * 32 + mt * 16 + qd * 4 + r;
                int t = t0 + nt * 16 + c;
                y[((size_t)(s * 256 + o)) * 256 + t] = acc[mt][nt][r] + bb[mt][r];
            }
}

// ---------------- launch ----------------
extern "C" void kernel_launch(void* const* d_in, const int* in_sizes, int n_in,
                              void* d_out, int out_size, void* d_ws, size_t ws_size,
                              hipStream_t stream) {
    const float* x      = (const float*)d_in[0];
    const float* time_  = (const float*)d_in[1];
    const float* w_qkv  = (const float*)d_in[2];
    const float* w_time = (const float*)d_in[3];
    const float* b_time = (const float*)d_in[4];
    const float* w_out  = (const float*)d_in[5];
    const float* b_out  = (const float*)d_in[6];
    float* y = (float*)d_out;
    char* ws = (char*)d_ws;

    bf16*  wqkv_bf  = (bf16*)(ws + 0);            //   786432 B
    bf16*  wtime_bf = (bf16*)(ws + 786432);       //   786432 B
    bf16*  wout_bf  = (bf16*)(ws + 1572864);      //   262144 B
    bf16*  mish_bf  = (bf16*)(ws + 1835008);      //   262144 B
    float* tembT    = (float*)(ws + 2097152);     //  3145728 B  [1536][512] global
    bf16*  xT       = (bf16*)(ws + 5242880);      // 33554432 B  per group
    bf16*  midT     = (bf16*)(ws + 206569472);    // 67108864 B  per group

    // global prep (once)
    k_cvt<<<384, 256, 0, stream>>>((const float4*)w_qkv, wqkv_bf);
    k_cvt<<<384, 256, 0, stream>>>((const float4*)w_time, wtime_bf);
    k_cvt<<<128, 256, 0, stream>>>((const float4*)w_out, wout_bf);
    k_mish<<<128, 256, 0, stream>>>((const float4*)time_, mish_bf);
    k_temb<<<dim3(12, 4), 256, 0, stream>>>(wtime_bf, mish_bf, b_time, tembT);

    // per-group pipeline
    for (int g = 0; g < NGRP; g++) {
        const float* xg = x + (size_t)g * SG * FF * TT;
        float*       yg = y + (size_t)g * SG * 256 * TT;
        const float* tg = tembT + (size_t)g * SG;
        k_xpose<<<SG * 16, 256, 0, stream>>>(xg, xT);
        k_fused<<<SG * 4, 512, 0, stream>>>(wqkv_bf, xT, tg, midT);
        k_out<<<4 * SG, 256, 0, stream>>>(wout_bf, midT, b_out, yg);
    }
}